// Round 2
// baseline (5547.760 us; speedup 1.0000x reference)
//
#include <hip/hip_runtime.h>

// NeuralODE SSP-RK3, z:[32,16,8192] fp32, W:[16,16,5], 100 steps, h=t/100.
// One kernel per step fuses all 3 RK stages via halo recompute:
//   slab = tile (244 cols) + 6 halo cols/side = 256 cols x 16 ch in LDS.
//   Garbage from slab edges propagates <=2 cols/stage; after 3 stages the
//   interior 244 cols are exact. BC (cells 0..9 <- val(10); L-10..L-1 <-
//   val(L-11)) applied in-LDS after stages 1,2 (edge blocks only) and at the
//   global store for stage 3. Ping-pong z between d_out and d_ws (16 MiB ws).

#define NCH    16
#define LL     8192
#define TX     244
#define HALO   6
#define SLAB   256          // TX + 2*HALO
#define SROW   272          // padded LDS row stride (floats); data at [PAD, PAD+SLAB)
#define PAD    4
#define NB     34           // ceil(LL / TX)
#define NSTEPS 100

__device__ __forceinline__ void conv4(const float* __restrict__ S, int c0, int og,
                                      const float* __restrict__ W, float acc[4][4]) {
#pragma unroll
  for (int o = 0; o < 4; ++o)
#pragma unroll
    for (int j = 0; j < 4; ++j) acc[o][j] = 0.0f;

#pragma unroll
  for (int i = 0; i < NCH; ++i) {
    const float* r = S + i * SROW + PAD + c0;
    float4 a0 = *(const float4*)(r - 4);   // cols c0-4..c0-1 (pad region for c0=0: finite junk)
    float4 a1 = *(const float4*)(r);       // cols c0..c0+3
    float4 a2 = *(const float4*)(r + 4);   // cols c0+4..c0+7
    float w[12] = {a0.x, a0.y, a0.z, a0.w, a1.x, a1.y, a1.z, a1.w, a2.x, a2.y, a2.z, a2.w};
#pragma unroll
    for (int o = 0; o < 4; ++o) {
#pragma unroll
      for (int k = 0; k < 5; ++k) {
        // og is wave-uniform (readfirstlane) -> scalar load from constant cache
        float wt = W[(og + o) * (NCH * 5) + i * 5 + k];
#pragma unroll
        for (int j = 0; j < 4; ++j) acc[o][j] += wt * w[2 + j + k];
      }
    }
  }
}

__device__ __forceinline__ void bc_fix(float* S, int x0, bool leftE, bool rightE, int tid) {
  if (leftE) {
    for (int idx = tid; idx < NCH * 10; idx += 256) {
      int o = idx / 10, g = idx - o * 10;
      S[o * SROW + PAD + 6 + g] = S[o * SROW + PAD + 16];   // gx 0..9 <- val(gx=10)
    }
  }
  if (rightE) {
    int ca = (LL - 11) - x0 + HALO;                          // col of gx = L-11
    for (int idx = tid; idx < NCH * 10; idx += 256) {
      int o = idx / 10, g = idx - o * 10;
      S[o * SROW + PAD + ca + 1 + g] = S[o * SROW + PAD + ca];
    }
  }
}

__global__ __launch_bounds__(256) void step_kernel(const float* __restrict__ in,
                                                   float* __restrict__ out,
                                                   const float* __restrict__ W,
                                                   const int* __restrict__ tptr) {
  __shared__ float S0[NCH * SROW];   // z slab (read-only after load)
  __shared__ float S1[NCH * SROW];   // k1, then k2

  const int b = blockIdx.y, bx = blockIdx.x;
  const int x0 = bx * TX;
  const bool leftE = (bx == 0), rightE = (bx == NB - 1);
  const float h = (float)(*tptr) / (float)NSTEPS;
  const float* __restrict__ inb = in + (size_t)b * NCH * LL;
  float* __restrict__ outb = out + (size_t)b * NCH * LL;
  const int tid = threadIdx.x;

  // Load z slab: col c <-> gx = x0 - 6 + c, clamped (clamped cols feed only
  // outputs that BC/halo-shrink discards).
  for (int idx = tid; idx < NCH * SLAB; idx += 256) {
    int row = idx >> 8, col = idx & 255;
    int gx = x0 - HALO + col;
    gx = min(max(gx, 0), LL - 1);
    S0[row * SROW + PAD + col] = inb[row * LL + gx];
  }
  __syncthreads();

  const int og = __builtin_amdgcn_readfirstlane((tid >> 6) * 4);  // 4 out-ch per wave
  const int c0 = (tid & 63) * 4;                                  // 4 cols per lane

  // Pointwise z stays in registers for all 3 stages.
  float zp[4][4];
#pragma unroll
  for (int o = 0; o < 4; ++o) {
    float4 v = *(const float4*)(S0 + (og + o) * SROW + PAD + c0);
    zp[o][0] = v.x; zp[o][1] = v.y; zp[o][2] = v.z; zp[o][3] = v.w;
  }

  float acc[4][4], t[4][4];

  // ---- stage 1: k1 = BC(z + h*conv(z)) ----
  conv4(S0, c0, og, W, acc);
#pragma unroll
  for (int o = 0; o < 4; ++o)
#pragma unroll
    for (int j = 0; j < 4; ++j) t[o][j] = zp[o][j] + h * acc[o][j];
#pragma unroll
  for (int o = 0; o < 4; ++o)
    *(float4*)(S1 + (og + o) * SROW + PAD + c0) = make_float4(t[o][0], t[o][1], t[o][2], t[o][3]);
  __syncthreads();
  if (leftE | rightE) { bc_fix(S1, x0, leftE, rightE, tid); __syncthreads(); }

  // ---- stage 2: k2 = BC(0.75 z + 0.25 k1 + 0.25 h conv(k1)) ----
  conv4(S1, c0, og, W, acc);
#pragma unroll
  for (int o = 0; o < 4; ++o)
#pragma unroll
    for (int j = 0; j < 4; ++j)
      t[o][j] = 0.75f * zp[o][j] + 0.25f * t[o][j] + 0.25f * h * acc[o][j];
  __syncthreads();   // all conv reads of k1 done before overwrite
#pragma unroll
  for (int o = 0; o < 4; ++o)
    *(float4*)(S1 + (og + o) * SROW + PAD + c0) = make_float4(t[o][0], t[o][1], t[o][2], t[o][3]);
  __syncthreads();
  if (leftE | rightE) { bc_fix(S1, x0, leftE, rightE, tid); __syncthreads(); }

  // ---- stage 3: z_new = BC(z/3 + 2/3 k2 + 2/3 h conv(k2)) ----
  conv4(S1, c0, og, W, acc);
  const float c13 = 1.0f / 3.0f, c23 = 2.0f / 3.0f;
#pragma unroll
  for (int o = 0; o < 4; ++o) {
    const int ch = og + o;
    float* __restrict__ po = outb + (size_t)ch * LL;
#pragma unroll
    for (int j = 0; j < 4; ++j) {
      const int c = c0 + j;
      const int gx = x0 - HALO + c;
      if (c < HALO || c >= HALO + TX || gx >= LL) continue;
      const float v = c13 * zp[o][j] + c23 * t[o][j] + c23 * h * acc[o][j];
      const bool gL = leftE && gx < 10;
      const bool gR = rightE && gx > LL - 11;
      if (!gL && !gR) po[gx] = v;
      if (leftE && gx == 10) {
#pragma unroll
        for (int g = 0; g < 10; ++g) po[g] = v;
      }
      if (rightE && gx == LL - 11) {
#pragma unroll
        for (int g = LL - 10; g < LL; ++g) po[g] = v;
      }
    }
  }
}

extern "C" void kernel_launch(void* const* d_in, const int* in_sizes, int n_in,
                              void* d_out, int out_size, void* d_ws, size_t ws_size,
                              hipStream_t stream) {
  const float* z0 = (const float*)d_in[0];
  const float* W  = (const float*)d_in[1];
  const int*   t  = (const int*)d_in[2];

  float* A = (float*)d_out;   // final result must land here (100 steps = even)
  float* B = (float*)d_ws;    // 16 MiB scratch only

  dim3 grid(NB, 32);
  dim3 block(256);

  // step 1: z0 -> B; then alternate B->A, A->B, ...; step 100 (even) ends in A.
  step_kernel<<<grid, block, 0, stream>>>(z0, B, W, t);
  for (int s = 2; s <= NSTEPS; ++s) {
    if (s & 1) step_kernel<<<grid, block, 0, stream>>>(A, B, W, t);
    else       step_kernel<<<grid, block, 0, stream>>>(B, A, W, t);
  }
}

// Round 3
// 1944.680 us; speedup vs baseline: 2.8528x; 2.8528x over previous
//
#include <hip/hip_runtime.h>

// NeuralODE SSP-RK3 via MFMA: z:[32,16,8192] fp32, W:[16,16,5], 100 steps.
// conv(16ch->16ch, k=5) per 16-col tile = 3x mfma_f32_16x16x32_bf16 with
// K-chunks = (tap pair) x (16 input channels). Intermediate state is fp32 in
// TRANSPOSED layout [b][x][ch] so B-fragments are single ds_read_b128 of 8
// channels at one x. Conv inputs/weights bf16; all pointwise RK math fp32.
// Per-step kernel fuses 3 RK stages with halo recompute (1 tile halo/side).
// Ping-pong: d_out (Q) <-> d_ws (P, 16 MiB). transpose(z0)->Q; odd steps Q->P,
// even P->Q; step 100 writes row-major into Q=d_out.

#define NCH    16
#define LL     8192
#define TX     256
#define NT     18          // tiles: 16 interior + 1 halo tile each side
#define SLABC  292         // slab cols, s in [0,292); global x = x0 - 18 + s
#define NBX    32
#define NSTEPS 100

typedef __bf16 bf16x8 __attribute__((ext_vector_type(8)));
typedef __bf16 bf16x4 __attribute__((ext_vector_type(4)));
typedef float  f32x4  __attribute__((ext_vector_type(4)));

// LDS layout: S[col][ch] bf16, 16 ch contiguous per col; XOR-swizzle the 8-ch
// half on col bit2 to spread the 8-bank col stride across 32 banks.
__device__ __forceinline__ int ldsIdx(int col, int ch) {
  return col * NCH + (ch ^ ((col & 4) << 1));
}

__global__ __launch_bounds__(256) void transpose_kernel(const float* __restrict__ in,
                                                        float* __restrict__ out) {
  const int b = blockIdx.y;
  const int x = blockIdx.x * 256 + threadIdx.x;
  const float* __restrict__ ib = in + (size_t)b * NCH * LL;
  float* __restrict__ ob = out + (size_t)b * NCH * LL;
  float v[NCH];
#pragma unroll
  for (int c = 0; c < NCH; ++c) v[c] = ib[c * LL + x];   // coalesced per channel
#pragma unroll
  for (int c = 0; c < NCH; c += 4)
    *(float4*)(ob + (size_t)x * NCH + c) = make_float4(v[c], v[c+1], v[c+2], v[c+3]);
}

__global__ __launch_bounds__(256, 4) void step_kernel(
    const float* __restrict__ zin,   // fp32 transposed [b][x][ch]
    float* __restrict__ zout,        // fp32 transposed, or row-major if finalStep
    const float* __restrict__ W,     // fp32 [o][i][k] 16x16x5
    const int* __restrict__ tptr, int finalStep)
{
  __shared__ __align__(16) __bf16 SA[SLABC * NCH];
  __shared__ __align__(16) __bf16 SB[SLABC * NCH];

  const int b = blockIdx.y, bx = blockIdx.x;
  const int x0 = bx * TX;
  const bool leftE = (bx == 0), rightE = (bx == NBX - 1);
  const float h = (float)(*tptr) / (float)NSTEPS;
  const int tid = threadIdx.x;
  const int lane = tid & 63, wv = tid >> 6;
  const int g = lane >> 4, n = lane & 15;

  const float* __restrict__ zb = zin + (size_t)b * NCH * LL;
  float* __restrict__ ob = zout + (size_t)b * NCH * LL;

  // ---- A fragments (weights, bf16, persistent). K-chunk c covers taps
  // kk = 2c + (g>>1); lane's 8 elems: in-ch i = (g&1)*8 + j; out-ch m = n.
  bf16x8 afrag[3];
#pragma unroll
  for (int c = 0; c < 3; ++c) {
    const int kk = c * 2 + (g >> 1);
#pragma unroll
    for (int j = 0; j < 8; ++j) {
      const int i = (g & 1) * 8 + j;
      const float wval = (kk < 5) ? W[n * (NCH * 5) + i * 5 + kk] : 0.0f;
      afrag[c][j] = (__bf16)wval;
    }
  }

  // ---- load z slab -> SA (bf16, transposed, swizzled) ----
  for (int q = tid; q < SLABC * 4; q += 256) {
    const int s = q >> 2, cg = (q & 3) * 4;
    int gx = x0 - 18 + s;
    gx = min(max(gx, 0), LL - 1);
    const float4 v = *(const float4*)(zb + (size_t)gx * NCH + cg);
    bf16x4 bv = { (__bf16)v.x, (__bf16)v.y, (__bf16)v.z, (__bf16)v.w };
    *(bf16x4*)(&SA[ldsIdx(s, cg)]) = bv;
  }
  __syncthreads();

  auto bcfix = [&](__bf16* S) {
    if (leftE && tid < 40) {          // ghosts x 0..9 (s 18..27) <- x=10 (s 28)
      const int gi = tid >> 2, cg = (tid & 3) * 4;
      *(bf16x4*)(&S[ldsIdx(18 + gi, cg)]) = *(const bf16x4*)(&S[ldsIdx(28, cg)]);
    }
    if (rightE && tid < 40) {         // ghosts x 8182..8191 (s 264..273) <- s 263
      const int gi = tid >> 2, cg = (tid & 3) * 4;
      *(bf16x4*)(&S[ldsIdx(264 + gi, cg)]) = *(const bf16x4*)(&S[ldsIdx(263, cg)]);
    }
  };

  f32x4 kf[5];
#pragma unroll
  for (int ti = 0; ti < 5; ++ti) kf[ti] = (f32x4){0.f, 0.f, 0.f, 0.f};

  // One RK stage: conv over Sin, v = az*z + ak*kf + agh*acc; kf <- v;
  // storeMode 0: bf16(v) -> Sout;  1: fp32 v -> global (interior tiles).
  auto stage = [&](const __bf16* Sin, __bf16* Sout, float az, float ak, float agh,
                   int storeMode) {
#pragma unroll
    for (int ti = 0; ti < 5; ++ti) {
      const int t = wv + 4 * ti;
      const bool active = (t < NT);
      const int tc = min(t, NT - 1);
      f32x4 acc = {0.f, 0.f, 0.f, 0.f};
#pragma unroll
      for (int c = 0; c < 3; ++c) {
        const int kk = c * 2 + (g >> 1);
        int s = 16 * tc + n + kk;
        s = min(s, SLABC - 1);
        // lanes with kk==5 have afrag==0, so any finite B value is fine
        bf16x8 bfrag = *(const bf16x8*)(&Sin[ldsIdx(s, (g & 1) * 8)]);
        acc = __builtin_amdgcn_mfma_f32_16x16x32_bf16(afrag[c], bfrag, acc, 0, 0, 0);
      }
      // pointwise: lane owns (x = tile col n, out-ch g*4 + r)
      const int xg = x0 - 16 + 16 * tc + n;
      const int xc = min(max(xg, 0), LL - 1);
      const f32x4 z4 = *(const f32x4*)(zb + (size_t)xc * NCH + g * 4);
      f32x4 v;
#pragma unroll
      for (int r = 0; r < 4; ++r) v[r] = az * z4[r] + ak * kf[ti][r] + agh * acc[r];
      kf[ti] = v;

      if (storeMode == 0) {
        if (active) {
          const int so = 16 * tc + n + 2;
          bf16x4 bv = { (__bf16)v[0], (__bf16)v[1], (__bf16)v[2], (__bf16)v[3] };
          *(bf16x4*)(&Sout[ldsIdx(so, g * 4)]) = bv;
        }
      } else {
        if (t >= 1 && t <= 16) {                       // interior tiles only
          const bool gl = leftE && (xg < 10);
          const bool gr = rightE && (xg > LL - 11);
          if (!gl && !gr) {
            if (!finalStep) {
              *(f32x4*)(ob + (size_t)xg * NCH + g * 4) = v;
            } else {
#pragma unroll
              for (int r = 0; r < 4; ++r) ob[(size_t)(g * 4 + r) * LL + xg] = v[r];
            }
          }
          if (leftE && xg == 10) {
            for (int gi = 0; gi < 10; ++gi) {
              if (!finalStep) *(f32x4*)(ob + (size_t)gi * NCH + g * 4) = v;
              else {
#pragma unroll
                for (int r = 0; r < 4; ++r) ob[(size_t)(g * 4 + r) * LL + gi] = v[r];
              }
            }
          }
          if (rightE && xg == LL - 11) {
            for (int gi = 0; gi < 10; ++gi) {
              if (!finalStep) *(f32x4*)(ob + (size_t)(LL - 10 + gi) * NCH + g * 4) = v;
              else {
#pragma unroll
                for (int r = 0; r < 4; ++r) ob[(size_t)(g * 4 + r) * LL + LL - 10 + gi] = v[r];
              }
            }
          }
        }
      }
    }
  };

  // stage 1: k1 = BC(z + h conv z)         (SA -> SB)
  stage(SA, SB, 1.0f, 0.0f, h, 0);
  __syncthreads();
  bcfix(SB);
  __syncthreads();

  // stage 2: k2 = BC(0.75 z + 0.25 k1 + 0.25 h conv k1)   (SB -> SA)
  stage(SB, SA, 0.75f, 0.25f, 0.25f * h, 0);
  __syncthreads();
  bcfix(SA);
  __syncthreads();

  // stage 3: z' = BC(z/3 + 2/3 k2 + 2/3 h conv k2)        (SA -> global)
  stage(SA, nullptr, 1.0f / 3.0f, 2.0f / 3.0f, (2.0f / 3.0f) * h, 1);
}

extern "C" void kernel_launch(void* const* d_in, const int* in_sizes, int n_in,
                              void* d_out, int out_size, void* d_ws, size_t ws_size,
                              hipStream_t stream) {
  const float* z0 = (const float*)d_in[0];
  const float* W  = (const float*)d_in[1];
  const int*   t  = (const int*)d_in[2];

  float* Q = (float*)d_out;   // transposed intermediate; final row-major dest
  float* P = (float*)d_ws;    // 16 MiB scratch

  dim3 grid(NBX, 32), block(256);
  transpose_kernel<<<grid, block, 0, stream>>>(z0, Q);

  for (int s = 1; s <= NSTEPS; ++s) {
    if (s & 1) step_kernel<<<grid, block, 0, stream>>>(Q, P, W, t, 0);
    else       step_kernel<<<grid, block, 0, stream>>>(P, Q, W, t, s == NSTEPS);
  }
}

// Round 5
// 1036.716 us; speedup vs baseline: 5.3513x; 1.8758x over previous
//
#include <hip/hip_runtime.h>

// NeuralODE SSP-RK3, z:[32,16,8192] fp32, W:[16,16,5], 100 steps, h=t/100.
// MFMA conv (16ch->16ch, k=5): per 16-col tile 3x mfma_f32_16x16x32_bf16,
// K-chunk = (tap pair) x (16 in-ch). State fp32, TRANSPOSED [b][x][ch];
// conv inputs/weights bf16 in LDS. 5 RK steps (15 stages) fused per kernel
// via halo recompute: slab = 256 interior + 32 halo cols/side (20 tiles);
// validity shrinks 2 cols/stage, 30 <= 32. fp32 state carried in registers
// across the 5 steps; BC via in-wave shuffles.
// R4 FIX: conv read col = write col + (kk-2); R3 dropped the -2 (2-cell
// drift/stage -> absmax 3.65). Write col is 16t+n, so read s=16t+n+kk-2.

#define NCH    16
#define LL     8192
#define TX     256
#define HALOC  32
#define SLABC  320          // 20 tiles of 16 cols; global x = x0 - 32 + s
#define NBX    32
#define NSTEPS 100
#define SPK    5            // steps fused per kernel
#define NKER   (NSTEPS / SPK)

typedef __bf16 bf16x8 __attribute__((ext_vector_type(8)));
typedef __bf16 bf16x4 __attribute__((ext_vector_type(4)));
typedef float  f32x4  __attribute__((ext_vector_type(4)));

// LDS: S[col][ch] bf16; XOR-swizzle 8-ch half on col bit2 (col stride = 8
// banks -> pairs of cols 2-way alias, free on CDNA4).
__device__ __forceinline__ int ldsIdx(int col, int ch) {
  return col * NCH + (ch ^ ((col & 4) << 1));
}

__global__ __launch_bounds__(256) void transpose_kernel(const float* __restrict__ in,
                                                        float* __restrict__ out) {
  const int b = blockIdx.y;
  const int x = blockIdx.x * 256 + threadIdx.x;
  const float* __restrict__ ib = in + (size_t)b * NCH * LL;
  float* __restrict__ ob = out + (size_t)b * NCH * LL;
  float v[NCH];
#pragma unroll
  for (int c = 0; c < NCH; ++c) v[c] = ib[c * LL + x];
#pragma unroll
  for (int c = 0; c < NCH; c += 4)
    *(float4*)(ob + (size_t)x * NCH + c) = make_float4(v[c], v[c+1], v[c+2], v[c+3]);
}

__global__ __launch_bounds__(256, 4) void multistep_kernel(
    const float* __restrict__ zin,   // fp32 transposed [b][x][ch]
    float* __restrict__ zout,        // fp32 transposed (row-major if finalKer)
    const float* __restrict__ W,     // fp32 [o][i][k]
    const int* __restrict__ tptr, int finalKer)
{
  __shared__ __align__(16) __bf16 S[2][SLABC * NCH];

  const int b = blockIdx.y, bx = blockIdx.x;
  const int x0 = bx * TX;
  const bool leftE = (bx == 0), rightE = (bx == NBX - 1);
  const float h = (float)(*tptr) / (float)NSTEPS;
  const int tid = threadIdx.x, lane = tid & 63, wv = tid >> 6;
  const int g = lane >> 4, n = lane & 15;

  const float* __restrict__ zb = zin + (size_t)b * NCH * LL;
  float* __restrict__ ob = zout + (size_t)b * NCH * LL;

  // A fragments (weights, bf16). K-chunk c: taps kk = 2c + (g>>1);
  // lane elems: in-ch i = (g&1)*8 + j; out-ch = n. kk==5 lanes get 0.
  bf16x8 afrag[3];
#pragma unroll
  for (int c = 0; c < 3; ++c) {
    const int kk = c * 2 + (g >> 1);
#pragma unroll
    for (int j = 0; j < 8; ++j) {
      const int i = (g & 1) * 8 + j;
      const float wval = (kk < 5) ? W[n * (NCH * 5) + i * 5 + kk] : 0.0f;
      afrag[c][j] = (__bf16)wval;
    }
  }

  // Load z slab -> S[0] (bf16, swizzled). Clamped cols only feed halo tiles.
  for (int q = tid; q < SLABC * 4; q += 256) {
    const int s = q >> 2, cg = (q & 3) * 4;
    int gx = x0 - HALOC + s;
    gx = min(max(gx, 0), LL - 1);
    const float4 v = *(const float4*)(zb + (size_t)gx * NCH + cg);
    bf16x4 bv = { (__bf16)v.x, (__bf16)v.y, (__bf16)v.z, (__bf16)v.w };
    *(bf16x4*)(&S[0][ldsIdx(s, cg)]) = bv;
  }

  // fp32 state in registers: thread owns (x = 16t+n, ch = g*4..g*4+3), t = wv+4*ti.
  f32x4 kz[5], kf[5];
#pragma unroll
  for (int ti = 0; ti < 5; ++ti) {
    const int t = wv + 4 * ti;
    int gx = x0 - HALOC + 16 * t + n;
    gx = min(max(gx, 0), LL - 1);
    kz[ti] = *(const f32x4*)(zb + (size_t)gx * NCH + g * 4);
    kf[ti] = (f32x4){0.f, 0.f, 0.f, 0.f};
  }
  __syncthreads();

  // One RK stage: v = az*z + ak*kf + agh*conv(RS); BC shuffles; kf<-v;
  // store bf16 to WS (or fp32 to global on the kernel's last stage).
  auto stage = [&](float az, float ak, float agh, int rb, bool updZ, bool toGlobal) {
    const __bf16* RS = S[rb];
    __bf16* WS = S[rb ^ 1];
#pragma unroll
    for (int ti = 0; ti < 5; ++ti) {
      const int t = wv + 4 * ti;
      f32x4 acc = {0.f, 0.f, 0.f, 0.f};
#pragma unroll
      for (int c = 0; c < 3; ++c) {
        const int kk = c * 2 + (g >> 1);
        int s = 16 * t + n + kk - 2;       // read col = write col + (kk-2)
        s = min(max(s, 0), SLABC - 1);     // clamped cols are shrink-invalid halo
        bf16x8 bfrag = *(const bf16x8*)(&RS[ldsIdx(s, (g & 1) * 8)]);
        acc = __builtin_amdgcn_mfma_f32_16x16x32_bf16(afrag[c], bfrag, acc, 0, 0, 0);
      }
      f32x4 v;
#pragma unroll
      for (int r = 0; r < 4; ++r)
        v[r] = az * kz[ti][r] + ak * kf[ti][r] + agh * acc[r];

      // BC in-register: ghosts x0..9 <- x=10 (t=2, lane n=10); x8182..8191 <- x=8181 (t=17, n=5)
      if (leftE && t == 2) {
#pragma unroll
        for (int r = 0; r < 4; ++r) {
          float sv = __shfl(v[r], (lane & 48) | 10, 64);
          if (n < 10) v[r] = sv;
        }
      }
      if (rightE && t == 17) {
#pragma unroll
        for (int r = 0; r < 4; ++r) {
          float sv = __shfl(v[r], (lane & 48) | 5, 64);
          if (n > 5) v[r] = sv;
        }
      }

      kf[ti] = v;
      if (updZ) kz[ti] = v;

      if (!toGlobal) {
        bf16x4 bv = { (__bf16)v[0], (__bf16)v[1], (__bf16)v[2], (__bf16)v[3] };
        *(bf16x4*)(&WS[ldsIdx(16 * t + n, g * 4)]) = bv;
      } else if (t >= 2 && t <= 17) {      // interior tiles: gx in [x0, x0+256)
        const int xg = x0 - HALOC + 16 * t + n;
        if (!finalKer) {
          *(f32x4*)(ob + (size_t)xg * NCH + g * 4) = v;
        } else {
#pragma unroll
          for (int r = 0; r < 4; ++r) ob[(size_t)(g * 4 + r) * LL + xg] = v[r];
        }
      }
    }
  };

  int rb = 0;
#pragma unroll 1
  for (int sp = 0; sp < SPK; ++sp) {
    const bool last = (sp == SPK - 1);
    stage(1.0f, 0.0f, h, rb, false, false);
    __syncthreads(); rb ^= 1;
    stage(0.75f, 0.25f, 0.25f * h, rb, false, false);
    __syncthreads(); rb ^= 1;
    stage(1.0f / 3.0f, 2.0f / 3.0f, (2.0f / 3.0f) * h, rb, true, last);
    if (!last) { __syncthreads(); rb ^= 1; }
  }
}

extern "C" void kernel_launch(void* const* d_in, const int* in_sizes, int n_in,
                              void* d_out, int out_size, void* d_ws, size_t ws_size,
                              hipStream_t stream) {
  const float* z0 = (const float*)d_in[0];
  const float* W  = (const float*)d_in[1];
  const int*   t  = (const int*)d_in[2];

  float* Q = (float*)d_out;   // transposed intermediate; final dest
  float* P = (float*)d_ws;    // 16 MiB scratch

  dim3 grid(NBX, 32), block(256);
  transpose_kernel<<<grid, block, 0, stream>>>(z0, Q);

  for (int k = 1; k <= NKER; ++k) {
    if (k & 1) multistep_kernel<<<grid, block, 0, stream>>>(Q, P, W, t, 0);
    else       multistep_kernel<<<grid, block, 0, stream>>>(P, Q, W, t, k == NKER);
  }
}